// Round 1
// baseline (379.216 us; speedup 1.0000x reference)
//
#include <hip/hip_runtime.h>

#define B_  16
#define L_  4096
#define D_  128

typedef __attribute__((ext_vector_type(8))) __bf16 bf16x8;
typedef __attribute__((ext_vector_type(4))) float f32x4;
typedef __attribute__((ext_vector_type(8))) unsigned short u16x8;
typedef __attribute__((ext_vector_type(4))) unsigned short u16x4;

__device__ __forceinline__ unsigned short f2bf(float f){
  unsigned u = __builtin_bit_cast(unsigned, f);
  u += 0x7fffu + ((u >> 16) & 1u);   // round-to-nearest-even
  return (unsigned short)(u >> 16);
}

__device__ __forceinline__ void gload16(const void* g, void* l){
  __builtin_amdgcn_global_load_lds(
      (const __attribute__((address_space(1))) unsigned int*)g,
      (__attribute__((address_space(3))) unsigned int*)l, 16, 0, 0);
}

// ---- fp32 -> bf16 cast (row-major), 8 elems/thread ----
__global__ void cvt_bf16_kernel(const float* __restrict__ in,
                                unsigned short* __restrict__ out, int n8){
  int i = blockIdx.x * blockDim.x + threadIdx.x;
  if (i >= n8) return;
  const float4* p = reinterpret_cast<const float4*>(in) + (size_t)i * 2;
  float4 a = p[0], b = p[1];
  u16x8 o;
  o[0]=f2bf(a.x); o[1]=f2bf(a.y); o[2]=f2bf(a.z); o[3]=f2bf(a.w);
  o[4]=f2bf(b.x); o[5]=f2bf(b.y); o[6]=f2bf(b.z); o[7]=f2bf(b.w);
  reinterpret_cast<u16x8*>(out)[i] = o;
}

// ---- V [B][L][D] fp32 -> Vt [B][D][L] bf16 (LDS tile transpose) ----
__global__ void transpose_v_kernel(const float* __restrict__ V,
                                   unsigned short* __restrict__ Vt){
  __shared__ unsigned short tile[64][65];
  const int k0 = blockIdx.x * 64, d0 = blockIdx.y * 64, b = blockIdx.z;
  const int tr = threadIdx.x >> 4, tc = threadIdx.x & 15;
  const float* src = V + ((size_t)b * L_ + k0) * D_ + d0;
#pragma unroll
  for (int p = 0; p < 4; ++p){
    int kl = p * 16 + tr;
    float4 v = *reinterpret_cast<const float4*>(src + (size_t)kl * D_ + tc * 4);
    tile[kl][tc*4+0] = f2bf(v.x);
    tile[kl][tc*4+1] = f2bf(v.y);
    tile[kl][tc*4+2] = f2bf(v.z);
    tile[kl][tc*4+3] = f2bf(v.w);
  }
  __syncthreads();
  unsigned short* dst = Vt + (size_t)b * D_ * L_ + (size_t)d0 * L_ + k0;
#pragma unroll
  for (int p = 0; p < 4; ++p){
    int dl = p * 16 + tr;
    u16x4 o;
    o[0] = tile[tc*4+0][dl];
    o[1] = tile[tc*4+1][dl];
    o[2] = tile[tc*4+2][dl];
    o[3] = tile[tc*4+3][dl];
    *reinterpret_cast<u16x4*>(dst + (size_t)dl * L_ + tc * 4) = o;
  }
}

// ---- fused flash attention ----
// block = 256 threads (4 waves). Each block: 64 q-rows (16/wave), batch = blockIdx.y.
// KV tiles of 64 keys. K LDS [64][256B] swizzled, Vt LDS [128][128B] swizzled,
// P LDS per-wave [16][72] bf16 (padded).
__global__ __launch_bounds__(256)
void attn_kernel(const unsigned short* __restrict__ Qb,
                 const unsigned short* __restrict__ Kb,
                 const unsigned short* __restrict__ Vt,
                 float* __restrict__ out){
  __shared__ char smem[16384 + 16384 + 4 * 2304];
  char* Klds = smem;
  char* Vlds = smem + 16384;
  const int tid = threadIdx.x;
  const int w = tid >> 6, l = tid & 63, g = l >> 4, l15 = l & 15;
  char* Plds = smem + 32768 + w * 2304;
  const int qt = blockIdx.x, b = blockIdx.y;

  // Q fragments: 16 q-rows per wave, row = l15, k-chunk kk covers d=[kk*32, kk*32+32)
  const unsigned short* qptr = Qb + ((size_t)b * L_ + (size_t)qt * 64 + w * 16 + l15) * D_;
  bf16x8 qf[4];
#pragma unroll
  for (int kk = 0; kk < 4; ++kk)
    qf[kk] = *reinterpret_cast<const bf16x8*>(qptr + kk * 32 + g * 8);

  const char* Kg = reinterpret_cast<const char*>(Kb + (size_t)b * L_ * D_);
  const char* Vg = reinterpret_cast<const char*>(Vt + (size_t)b * (size_t)D_ * L_);

  f32x4 O[8];
#pragma unroll
  for (int i = 0; i < 8; ++i) O[i] = (f32x4){0.f, 0.f, 0.f, 0.f};
  float m2[4], ln[4];
#pragma unroll
  for (int r = 0; r < 4; ++r){ m2[r] = -1e30f; ln[r] = 0.f; }

  constexpr float SCALE_L2E = 1.4426950408889634f / 11.313708498984761f;

  for (int t = 0; t < L_ / 64; ++t){
    const int kv0 = t * 64;
    __syncthreads();   // previous tile's LDS reads complete

    // stage K tile: rows [w*16, w*16+16), linear LDS, inverse-swizzled global src
#pragma unroll
    for (int j = 0; j < 4; ++j){
      int row = w * 16 + j * 4 + (l >> 4);
      int cb  = (l & 15) * 16;
      int gcb = cb ^ ((row & 7) << 4);
      gload16(Kg + (size_t)(kv0 + row) * 256 + gcb, Klds + w * 4096 + j * 1024);
    }
    // stage V^T tile: rows (d) [w*32, w*32+32)
#pragma unroll
    for (int j = 0; j < 4; ++j){
      int row = w * 32 + j * 8 + (l >> 3);
      int cb  = (l & 7) * 16;
      int gcb = cb ^ ((row & 7) << 4);
      gload16(Vg + (size_t)row * (L_ * 2) + kv0 * 2 + gcb, Vlds + w * 4096 + j * 1024);
    }
    __syncthreads();   // drains vmcnt: K,V visible to all waves

    // S = Q K^T  (16q x 64k per wave)
    f32x4 s[4];
#pragma unroll
    for (int kt = 0; kt < 4; ++kt){
      f32x4 acc = (f32x4){0.f, 0.f, 0.f, 0.f};
#pragma unroll
      for (int kk = 0; kk < 4; ++kk){
        const int row = kt * 16 + l15;
        const int c2 = (kk * 64 + g * 16) ^ ((row & 7) << 4);
        bf16x8 kf = *reinterpret_cast<const bf16x8*>(Klds + row * 256 + c2);
        acc = __builtin_amdgcn_mfma_f32_16x16x32_bf16(qf[kk], kf, acc, 0, 0, 0);
      }
      s[kt] = acc;
    }

    // online softmax (exp2 domain); S value at (q = g*4+r, key = kt*16+l15)
    float tmax[4];
#pragma unroll
    for (int r = 0; r < 4; ++r) tmax[r] = -1e30f;
#pragma unroll
    for (int kt = 0; kt < 4; ++kt)
#pragma unroll
      for (int r = 0; r < 4; ++r) tmax[r] = fmaxf(tmax[r], s[kt][r]);
#pragma unroll
    for (int r = 0; r < 4; ++r) tmax[r] *= SCALE_L2E;
#pragma unroll
    for (int mk = 1; mk < 16; mk <<= 1)
#pragma unroll
      for (int r = 0; r < 4; ++r) tmax[r] = fmaxf(tmax[r], __shfl_xor(tmax[r], mk));

    float corr[4], psum[4];
#pragma unroll
    for (int r = 0; r < 4; ++r){
      float mn = fmaxf(m2[r], tmax[r]);
      corr[r] = exp2f(m2[r] - mn);
      m2[r] = mn;
      psum[r] = 0.f;
    }
#pragma unroll
    for (int kt = 0; kt < 4; ++kt){
#pragma unroll
      for (int r = 0; r < 4; ++r){
        float p = exp2f(s[kt][r] * SCALE_L2E - m2[r]);
        psum[r] += p;
        *reinterpret_cast<unsigned short*>(Plds + (g * 4 + r) * 144 + (kt * 16 + l15) * 2) = f2bf(p);
      }
    }
#pragma unroll
    for (int mk = 1; mk < 16; mk <<= 1)
#pragma unroll
      for (int r = 0; r < 4; ++r) psum[r] += __shfl_xor(psum[r], mk);
#pragma unroll
    for (int r = 0; r < 4; ++r) ln[r] = ln[r] * corr[r] + psum[r];
#pragma unroll
    for (int dt = 0; dt < 8; ++dt)
#pragma unroll
      for (int r = 0; r < 4; ++r) O[dt][r] *= corr[r];

    // cross-lane P handoff through LDS (same wave): wait for ds_writes
    asm volatile("s_waitcnt lgkmcnt(0)" ::: "memory");

    // O += P V
#pragma unroll
    for (int c = 0; c < 2; ++c){
      bf16x8 pf = *reinterpret_cast<const bf16x8*>(Plds + l15 * 144 + c * 64 + g * 16);
#pragma unroll
      for (int dt = 0; dt < 8; ++dt){
        const int row = dt * 16 + l15;
        const int c2 = (c * 64 + g * 16) ^ ((row & 7) << 4);
        bf16x8 vf = *reinterpret_cast<const bf16x8*>(Vlds + row * 128 + c2);
        O[dt] = __builtin_amdgcn_mfma_f32_16x16x32_bf16(pf, vf, O[dt], 0, 0, 0);
      }
    }
  }

  // epilogue: normalize and store fp32
  float* outp = out + ((size_t)b * L_ + (size_t)qt * 64 + w * 16) * D_;
#pragma unroll
  for (int r = 0; r < 4; ++r){
    float inv = 1.0f / ln[r];
#pragma unroll
    for (int dt = 0; dt < 8; ++dt)
      outp[(size_t)(g * 4 + r) * D_ + dt * 16 + l15] = O[dt][r] * inv;
  }
}

extern "C" void kernel_launch(void* const* d_in, const int* in_sizes, int n_in,
                              void* d_out, int out_size, void* d_ws, size_t ws_size,
                              hipStream_t stream){
  const float* Q = (const float*)d_in[0];
  const float* K = (const float*)d_in[1];
  const float* V = (const float*)d_in[2];
  float* out = (float*)d_out;

  const size_t NE = (size_t)B_ * L_ * D_;       // 8,388,608 elems per tensor
  unsigned short* qb = (unsigned short*)d_ws;   // bf16 Q  [B][L][D]
  unsigned short* kb = qb + NE;                 // bf16 K  [B][L][D]
  unsigned short* vt = kb + NE;                 // bf16 V^T [B][D][L]

  int n8 = (int)(NE / 8);
  cvt_bf16_kernel<<<dim3(n8 / 256), 256, 0, stream>>>(Q, qb, n8);
  cvt_bf16_kernel<<<dim3(n8 / 256), 256, 0, stream>>>(K, kb, n8);
  transpose_v_kernel<<<dim3(L_ / 64, D_ / 64, B_), 256, 0, stream>>>(V, vt);
  attn_kernel<<<dim3(L_ / 64, B_), 256, 0, stream>>>(qb, kb, vt, out);
}

// Round 2
// 195.056 us; speedup vs baseline: 1.9441x; 1.9441x over previous
//
#include <hip/hip_runtime.h>

#define B_  16
#define L_  4096
#define D_  128
#define NT  (L_ / 64)

typedef __attribute__((ext_vector_type(8)))  __bf16 bf16x8;
typedef __attribute__((ext_vector_type(2)))  __bf16 bf16x2;
typedef __attribute__((ext_vector_type(16))) float  f32x16;
typedef __attribute__((ext_vector_type(4)))  float  f32x4;
typedef __attribute__((ext_vector_type(4)))  int    i32x4;
typedef __attribute__((ext_vector_type(8)))  unsigned short u16x8;
typedef __attribute__((ext_vector_type(4)))  unsigned short u16x4;

#ifndef __has_builtin
#define __has_builtin(x) 0
#endif
#if __has_builtin(__builtin_amdgcn_permlane32_swap)
#define HAVE_PLSWAP 1
#else
#define HAVE_PLSWAP 0
#endif

__device__ __forceinline__ unsigned short f2bf(float f){
  unsigned u = __builtin_bit_cast(unsigned, f);
  u += 0x7fffu + ((u >> 16) & 1u);   // RNE
  return (unsigned short)(u >> 16);
}

__device__ __forceinline__ int packbf(float a, float b){
  bf16x2 t; t[0] = (__bf16)a; t[1] = (__bf16)b;
  return __builtin_bit_cast(int, t);
}

__device__ __forceinline__ void gload16(const void* g, void* l){
  __builtin_amdgcn_global_load_lds(
      (const __attribute__((address_space(1))) unsigned int*)g,
      (__attribute__((address_space(3))) unsigned int*)l, 16, 0, 0);
}

// ---- fp32 -> bf16 cast (row-major), 8 elems/thread ----
__global__ void cvt_bf16_kernel(const float* __restrict__ in,
                                unsigned short* __restrict__ out, int n8){
  int i = blockIdx.x * blockDim.x + threadIdx.x;
  if (i >= n8) return;
  const float4* p = reinterpret_cast<const float4*>(in) + (size_t)i * 2;
  float4 a = p[0], b = p[1];
  u16x8 o;
  o[0]=f2bf(a.x); o[1]=f2bf(a.y); o[2]=f2bf(a.z); o[3]=f2bf(a.w);
  o[4]=f2bf(b.x); o[5]=f2bf(b.y); o[6]=f2bf(b.z); o[7]=f2bf(b.w);
  reinterpret_cast<u16x8*>(out)[i] = o;
}

// ---- V [B][L][D] fp32 -> Vt [B][D][L] bf16 ----
__global__ void transpose_v_kernel(const float* __restrict__ V,
                                   unsigned short* __restrict__ Vt){
  __shared__ unsigned short tile[64][65];
  const int k0 = blockIdx.x * 64, d0 = blockIdx.y * 64, b = blockIdx.z;
  const int tr = threadIdx.x >> 4, tc = threadIdx.x & 15;
  const float* src = V + ((size_t)b * L_ + k0) * D_ + d0;
#pragma unroll
  for (int p = 0; p < 4; ++p){
    int kl = p * 16 + tr;
    float4 v = *reinterpret_cast<const float4*>(src + (size_t)kl * D_ + tc * 4);
    tile[kl][tc*4+0] = f2bf(v.x);
    tile[kl][tc*4+1] = f2bf(v.y);
    tile[kl][tc*4+2] = f2bf(v.z);
    tile[kl][tc*4+3] = f2bf(v.w);
  }
  __syncthreads();
  unsigned short* dst = Vt + (size_t)b * D_ * L_ + (size_t)d0 * L_ + k0;
#pragma unroll
  for (int p = 0; p < 4; ++p){
    int dl = p * 16 + tr;
    u16x4 o;
    o[0] = tile[tc*4+0][dl];
    o[1] = tile[tc*4+1][dl];
    o[2] = tile[tc*4+2][dl];
    o[3] = tile[tc*4+3][dl];
    *reinterpret_cast<u16x4*>(dst + (size_t)dl * L_ + tc * 4) = o;
  }
}

// Build one PV A-operand chunk (16 keys) from per-lane P values.
// a0..a7 are this lane's 8 P values for this chunk (keys {0-3,8-11}+4hi).
__device__ __forceinline__ bf16x8 mkchunk(float a0,float a1,float a2,float a3,
                                          float a4,float a5,float a6,float a7,
                                          int hi){
  int x0 = packbf(a0,a1), x1 = packbf(a2,a3);
  int x2 = packbf(a4,a5), x3 = packbf(a6,a7);
  int W0, W1, W2, W3;
#if HAVE_PLSWAP
  {
    auto r = __builtin_amdgcn_permlane32_swap((unsigned)x0, (unsigned)x2, false, false);
    W0 = (int)r[0]; W2 = (int)r[1];
  }
  {
    auto r = __builtin_amdgcn_permlane32_swap((unsigned)x1, (unsigned)x3, false, false);
    W1 = (int)r[0]; W3 = (int)r[1];
  }
  (void)hi;
#else
  int y0 = __shfl_xor(x0, 32), y1 = __shfl_xor(x1, 32);
  int y2 = __shfl_xor(x2, 32), y3 = __shfl_xor(x3, 32);
  W0 = hi ? y2 : x0;  W1 = hi ? y3 : x1;
  W2 = hi ? x2 : y0;  W3 = hi ? x3 : y1;
#endif
  i32x4 ww; ww[0]=W0; ww[1]=W1; ww[2]=W2; ww[3]=W3;
  return __builtin_bit_cast(bf16x8, ww);
}

// ---- fused flash attention: 8 waves, 32 q-rows/wave, KVBLK=64, swapped QK^T ----
__global__ __launch_bounds__(512, 2)
void attn_kernel(const unsigned short* __restrict__ Qb,
                 const unsigned short* __restrict__ Kb,
                 const unsigned short* __restrict__ Vt,
                 float* __restrict__ out){
  __shared__ char smem[65536];          // K dbuf 2x16KB + V^T dbuf 2x16KB
  char* Klds = smem;
  char* Vlds = smem + 32768;

  const int tid = threadIdx.x;
  const int w = tid >> 6, l = tid & 63;
  const int row = l & 31, hi = l >> 5;
  const int swz = (row & 7) << 4;
  const int b = blockIdx.x, qt = blockIdx.y;   // batch-major: 2 batches/XCD -> K/V L2-resident

  // Q fragments (B-operand): lane holds Q[q = l&31][c*16 + hi*8 + j]
  const unsigned short* qptr =
      Qb + ((size_t)b * L_ + (size_t)qt * 256 + w * 32 + row) * D_;
  bf16x8 qf[8];
#pragma unroll
  for (int c = 0; c < 8; ++c)
    qf[c] = *reinterpret_cast<const bf16x8*>(qptr + c * 16 + hi * 8);

  const char* Kg = (const char*)(Kb + (size_t)b * L_ * D_);
  const char* Vg = (const char*)(Vt + (size_t)b * (size_t)D_ * L_);

  f32x16 o[4];
#pragma unroll
  for (int n = 0; n < 4; ++n)
#pragma unroll
    for (int i = 0; i < 16; ++i) o[n][i] = 0.f;
  float m = -1e30f, ln = 0.f;

  constexpr float SCALE_L2E = 1.4426950408889634f / 11.313708498984761f;
  constexpr float THR = 11.0f;   // defer-max threshold (exp2 domain)

  auto STAGE = [&](int buf, int t){
    const int kv0 = t * 64;
#pragma unroll
    for (int j = 0; j < 2; ++j){
      int idx = j * 512 + tid;
      int kr = idx >> 4, kc = (idx & 15) << 4;
      gload16(Kg + (size_t)(kv0 + kr) * 256 + (kc ^ ((kr & 7) << 4)),
              Klds + buf * 16384 + idx * 16);
    }
#pragma unroll
    for (int j = 0; j < 2; ++j){
      int idx = j * 512 + tid;
      int vr = idx >> 3, vc = (idx & 7) << 4;
      gload16(Vg + (size_t)vr * (L_ * 2) + (size_t)kv0 * 2 + (vc ^ ((vr & 7) << 4)),
              Vlds + buf * 16384 + idx * 16);
    }
  };

  STAGE(0, 0);
  __syncthreads();
  int cur = 0;

  for (int t = 0; t < NT; ++t){
    if (t + 1 < NT) STAGE(cur ^ 1, t + 1);   // prefetch overlaps compute

    const char* Kc = Klds + cur * 16384;
    const char* Vc = Vlds + cur * 16384;

    // S^T = K . Q^T : lane holds q = l&31; keys (reg&3)+8*(reg>>2)+4*hi (+32 for s1)
    f32x16 s0 = {0.f,0,0,0, 0,0,0,0, 0,0,0,0, 0,0,0,0};
    f32x16 s1 = {0.f,0,0,0, 0,0,0,0, 0,0,0,0, 0,0,0,0};
#pragma unroll
    for (int c = 0; c < 8; ++c){
      bf16x8 kf0 = *(const bf16x8*)(Kc + row * 256 + ((c * 32 + hi * 16) ^ swz));
      bf16x8 kf1 = *(const bf16x8*)(Kc + (row + 32) * 256 + ((c * 32 + hi * 16) ^ swz));
      s0 = __builtin_amdgcn_mfma_f32_32x32x16_bf16(kf0, qf[c], s0, 0, 0, 0);
      s1 = __builtin_amdgcn_mfma_f32_32x32x16_bf16(kf1, qf[c], s1, 0, 0, 0);
    }

    // in-register online softmax (exp2 domain), state per lane (q = l&31)
    float mx = -1e30f;
#pragma unroll
    for (int i = 0; i < 16; ++i) mx = fmaxf(mx, fmaxf(s0[i], s1[i]));
    mx *= SCALE_L2E;
    mx = fmaxf(mx, __shfl_xor(mx, 32));

    if (!__all(mx <= m + THR)){            // defer-max: rescale only on real growth
      float mn = fmaxf(m, mx);
      float corr = __builtin_amdgcn_exp2f(m - mn);
      m = mn; ln *= corr;
#pragma unroll
      for (int n = 0; n < 4; ++n)
#pragma unroll
        for (int i = 0; i < 16; ++i) o[n][i] *= corr;
    }

    f32x16 p0, p1;
#pragma unroll
    for (int i = 0; i < 16; ++i){
      p0[i] = __builtin_amdgcn_exp2f(fmaf(s0[i], SCALE_L2E, -m));
      p1[i] = __builtin_amdgcn_exp2f(fmaf(s1[i], SCALE_L2E, -m));
    }
    float ps = 0.f;
#pragma unroll
    for (int i = 0; i < 16; ++i) ps += p0[i] + p1[i];
    ps += __shfl_xor(ps, 32);
    ln += ps;

    // P^T B-operand fragments (4 chunks of 16 keys)
    bf16x8 pa0 = mkchunk(p0[0],p0[1],p0[2],p0[3],p0[4],p0[5],p0[6],p0[7], hi);
    bf16x8 pa1 = mkchunk(p0[8],p0[9],p0[10],p0[11],p0[12],p0[13],p0[14],p0[15], hi);
    bf16x8 pa2 = mkchunk(p1[0],p1[1],p1[2],p1[3],p1[4],p1[5],p1[6],p1[7], hi);
    bf16x8 pa3 = mkchunk(p1[8],p1[9],p1[10],p1[11],p1[12],p1[13],p1[14],p1[15], hi);

    // O^T += V^T . P^T : lane holds col q = l&31, rows d
#pragma unroll
    for (int n = 0; n < 4; ++n){
      const int vrow = n * 32 + row;
      bf16x8 vf0 = *(const bf16x8*)(Vc + vrow * 128 + ((0 * 32 + hi * 16) ^ swz));
      bf16x8 vf1 = *(const bf16x8*)(Vc + vrow * 128 + ((1 * 32 + hi * 16) ^ swz));
      bf16x8 vf2 = *(const bf16x8*)(Vc + vrow * 128 + ((2 * 32 + hi * 16) ^ swz));
      bf16x8 vf3 = *(const bf16x8*)(Vc + vrow * 128 + ((3 * 32 + hi * 16) ^ swz));
      o[n] = __builtin_amdgcn_mfma_f32_32x32x16_bf16(vf0, pa0, o[n], 0, 0, 0);
      o[n] = __builtin_amdgcn_mfma_f32_32x32x16_bf16(vf1, pa1, o[n], 0, 0, 0);
      o[n] = __builtin_amdgcn_mfma_f32_32x32x16_bf16(vf2, pa2, o[n], 0, 0, 0);
      o[n] = __builtin_amdgcn_mfma_f32_32x32x16_bf16(vf3, pa3, o[n], 0, 0, 0);
    }

    __syncthreads();   // drains prefetch vmcnt + all reads of cur buffer
    cur ^= 1;
  }

  // epilogue: normalize, store fp32. Lane writes q = l&31 row, d = n*32+8*rq+4*hi+j
  float inv = 1.0f / ln;
  float* outp = out + ((size_t)b * L_ + (size_t)qt * 256 + w * 32 + row) * D_;
#pragma unroll
  for (int n = 0; n < 4; ++n)
#pragma unroll
    for (int rq = 0; rq < 4; ++rq){
      f32x4 v4;
      v4[0] = o[n][rq*4+0] * inv;
      v4[1] = o[n][rq*4+1] * inv;
      v4[2] = o[n][rq*4+2] * inv;
      v4[3] = o[n][rq*4+3] * inv;
      *reinterpret_cast<f32x4*>(outp + n * 32 + rq * 8 + hi * 4) = v4;
    }
}

extern "C" void kernel_launch(void* const* d_in, const int* in_sizes, int n_in,
                              void* d_out, int out_size, void* d_ws, size_t ws_size,
                              hipStream_t stream){
  const float* Q = (const float*)d_in[0];
  const float* K = (const float*)d_in[1];
  const float* V = (const float*)d_in[2];
  float* out = (float*)d_out;

  const size_t NE = (size_t)B_ * L_ * D_;
  unsigned short* qb = (unsigned short*)d_ws;   // bf16 Q  [B][L][D]
  unsigned short* kb = qb + NE;                 // bf16 K  [B][L][D]
  unsigned short* vt = kb + NE;                 // bf16 V^T [B][D][L]

  int n8 = (int)(NE / 8);
  cvt_bf16_kernel<<<dim3(n8 / 256), 256, 0, stream>>>(Q, qb, n8);
  cvt_bf16_kernel<<<dim3(n8 / 256), 256, 0, stream>>>(K, kb, n8);
  transpose_v_kernel<<<dim3(L_ / 64, D_ / 64, B_), 256, 0, stream>>>(V, vt);
  attn_kernel<<<dim3(B_, L_ / 256), 512, 0, stream>>>(qb, kb, vt, out);
}